// Round 8
// baseline (5358.254 us; speedup 1.0000x reference)
//
#include <hip/hip_runtime.h>

typedef __attribute__((ext_vector_type(8))) short short8;
typedef __attribute__((ext_vector_type(4))) short short4v;
typedef __attribute__((ext_vector_type(4))) float floatx4;

#define SEQ 512
#define BS  64
#define HID 1024
#define G4  4096
#define NBLK 128
#define NGRP 4    // batch groups
#define BPG  32   // blocks per group
#define GBS  16   // batch rows per group
#define UPB  32   // hidden units per block

__device__ __forceinline__ unsigned short f2b(float f) {
  union { float f; unsigned u; } v; v.f = f;
  return (unsigned short)((v.u + 0x7FFFu + ((v.u >> 16) & 1u)) >> 16);
}
__device__ __forceinline__ float b2f(unsigned short s) {
  union { unsigned u; float f; } v; v.u = ((unsigned)s) << 16;
  return v.f;
}

// device-coherent (cross-XCD) async global->LDS: aux=17 = SC0|SC1
__device__ __forceinline__ void gload_lds16_cc(const void* g, void* l) {
  __builtin_amdgcn_global_load_lds(
      (const __attribute__((address_space(1))) unsigned int*)g,
      (__attribute__((address_space(3))) unsigned int*)l,
      16, 0, 17);
}

// ---- weight transpose+convert: W[1024][4096] f32 -> WT[4096][1024] bf16
__global__ void wtrans(const float* __restrict__ W, short* __restrict__ WT) {
  __shared__ float tile[32][33];
  const int tx = threadIdx.x, ty = threadIdx.y;
  const int n0 = blockIdx.x << 5, k0 = blockIdx.y << 5;
#pragma unroll
  for (int i = 0; i < 32; i += 8)
    tile[ty + i][tx] = W[(size_t)(k0 + ty + i) * G4 + n0 + tx];
  __syncthreads();
#pragma unroll
  for (int i = 0; i < 32; i += 8)
    WT[(size_t)(n0 + ty + i) * 1024 + k0 + tx] = (short)f2b(tile[tx][ty + i]);
}

// ---- standalone projection GEMM (prologue only): out[M][4096] = A @ WT^T + b
__global__ __launch_bounds__(256)
void gemm_xw(const float* __restrict__ A, const short* __restrict__ BT,
             const float* __restrict__ bias, void* __restrict__ xw, int xw_f32) {
  __shared__ short Al[128 * 40];
  __shared__ short Bl[128 * 40];
  const int tid = threadIdx.x;
  const int wave = tid >> 6, lane = tid & 63;
  const int lr = lane & 15, lh = lane >> 4;
  const int wm = wave >> 1, wn = wave & 1;
  const int m0 = blockIdx.y << 7;
  const int n0 = blockIdx.x << 7;
  const int arow = tid >> 1, akc = tid & 1;

  const float* aptr = A + (size_t)(m0 + arow) * 1024 + akc * 16;
  const short* bptr = BT + (size_t)(n0 + arow) * 1024 + akc * 16;

  floatx4 acc[4][4] = {};
  floatx4 fa[4];
  short8 pb0, pb1;
#pragma unroll
  for (int j = 0; j < 4; ++j) fa[j] = __builtin_nontemporal_load((const floatx4*)(aptr + 4 * j));
  pb0 = *(const short8*)(bptr);
  pb1 = *(const short8*)(bptr + 8);

  for (int it = 0; it < 32; ++it) {
    __syncthreads();
    unsigned short us[16];
#pragma unroll
    for (int j = 0; j < 4; ++j)
#pragma unroll
      for (int e = 0; e < 4; ++e) us[4 * j + e] = f2b(fa[j][e]);
    short8 s0, s1;
#pragma unroll
    for (int e = 0; e < 8; ++e) { s0[e] = (short)us[e]; s1[e] = (short)us[8 + e]; }
    *(short8*)&Al[arow * 40 + akc * 16 + 0] = s0;
    *(short8*)&Al[arow * 40 + akc * 16 + 8] = s1;
    *(short8*)&Bl[arow * 40 + akc * 16 + 0] = pb0;
    *(short8*)&Bl[arow * 40 + akc * 16 + 8] = pb1;
    __syncthreads();
    if (it < 31) {
      const int k0 = (it + 1) << 5;
#pragma unroll
      for (int j = 0; j < 4; ++j) fa[j] = __builtin_nontemporal_load((const floatx4*)(aptr + k0 + 4 * j));
      pb0 = *(const short8*)(bptr + k0);
      pb1 = *(const short8*)(bptr + k0 + 8);
    }
    short8 af[4], bf[4];
#pragma unroll
    for (int mt = 0; mt < 4; ++mt) af[mt] = *(const short8*)&Al[(wm * 64 + mt * 16 + lr) * 40 + lh * 8];
#pragma unroll
    for (int nt = 0; nt < 4; ++nt) bf[nt] = *(const short8*)&Bl[(wn * 64 + nt * 16 + lr) * 40 + lh * 8];
#pragma unroll
    for (int mt = 0; mt < 4; ++mt)
#pragma unroll
      for (int nt = 0; nt < 4; ++nt)
        acc[mt][nt] = __builtin_amdgcn_mfma_f32_16x16x32_bf16(af[mt], bf[nt], acc[mt][nt], 0, 0, 0);
  }
#pragma unroll
  for (int nt = 0; nt < 4; ++nt) {
    const int gcol = n0 + wn * 64 + nt * 16 + lr;
    const float bv = bias[gcol];
#pragma unroll
    for (int mt = 0; mt < 4; ++mt)
#pragma unroll
      for (int r = 0; r < 4; ++r) {
        const int grow = m0 + wm * 64 + mt * 16 + lh * 4 + r;
        const float v = acc[mt][nt][r] + bv;
        if (xw_f32) __builtin_nontemporal_store(v, (float*)xw + (size_t)grow * G4 + gcol);
        else        __builtin_nontemporal_store(f2b(v), (unsigned short*)xw + (size_t)grow * G4 + gcol);
      }
  }
}

struct FusedArgs {
  // scan (blocks 0..127): recurrence for chunk [t0,t1) reading xw
  const void* xw;
  const short* wt_hi;
  unsigned short* hbuf;    // [2][64*1024] bf16 ping-pong (coherent traffic)
  float* cbuf;             // [64*1024] f32 persistent cell state
  unsigned int* flags;     // [NBLK] u32 padded to 64B
  float* hs;               // [512][64][1024] f32 output
  float* h_final;
  float* c_final;
  int t0, t1, wr_final;
  // gemm (blocks 128..255): xw for the NEXT chunk -> dst
  const float* A;          // [Mrows][1024] f32
  const short* BT;         // WT [4096][1024] bf16
  const float* bias;
  void* dst;
  int Mrows, genable;
};

// ---- scan body: r5/r6 geometry; streaming traffic nt, throttled poll
template<int XW_F32>
__device__ __forceinline__ void scan_body(const FusedArgs& p, char* smem) {
  // [0,32768): h tile [16 rows][2048B] XOR-swizzled; [32768,+16896): gsm
  float* gsm = (float*)(smem + 32768);
  const int tid = threadIdx.x;
  const int wave = tid >> 6, lane = tid & 63;
  const int lr = lane & 15, lh = lane >> 4;
  const int nt = wave >> 1;              // N tile 0..7
  const int kh = wave & 1;               // K half 0..1
  const int blk = blockIdx.x;
  const int g = blk >> 5;                // batch group 0..3
  const int ub_idx = blk & 31;           // unit-block within hidden dim
  const int gcol = ((nt >> 1) << 10) + ub_idx * UPB + ((nt & 1) << 4) + lr;

  short8 breg[16];
  {
    const short* wp = p.wt_hi + (size_t)gcol * HID + (kh << 9) + (lh << 3);
#pragma unroll
    for (int kk = 0; kk < 16; ++kk) breg[kk] = *(const short8*)(wp + (kk << 5));
  }

  const int b_loc = tid >> 5, u_loc = tid & 31;
  const int ci = ((g * GBS + b_loc) << 10) + ub_idx * UPB + u_loc;
  float creg = (tid < 512) ? p.cbuf[ci] : 0.f;

  const int asw = lr & 7;
  const unsigned long long fad =
      (unsigned long long)(p.flags + ((size_t)(g * BPG) + (lane & 31)) * 16);

  for (int t = p.t0; t < p.t1; ++t) {
    // ---- xw prefetch BEFORE the poll (nt: don't pollute LLC)
    float xv[4] = {0.f, 0.f, 0.f, 0.f};
    if (kh == 0) {
#pragma unroll
      for (int r = 0; r < 4; ++r) {
        const size_t rowi = (size_t)(t - p.t0) * BS + g * GBS + (lh << 2) + r;
        if (XW_F32) xv[r] = __builtin_nontemporal_load((const float*)p.xw + rowi * G4 + gcol);
        else        xv[r] = b2f(__builtin_nontemporal_load((const unsigned short*)p.xw + rowi * G4 + gcol));
      }
    }

    // ---- barrier-in: wait until the group has published h for step t
    if (t > 0 && wave == 0) {
      unsigned f0;
      for (;;) {
        asm volatile("global_load_dword %0, %1, off sc0 sc1\n\t"
                     "s_waitcnt vmcnt(0)"
                     : "=v"(f0) : "v"(fad) : "memory");
        if (__all(f0 >= (unsigned)t)) break;
        __builtin_amdgcn_s_sleep(1);   // throttle LLC poll traffic
      }
    }
    __syncthreads();

    const unsigned short* hb = p.hbuf + (size_t)(t & 1) * (BS * HID) + (size_t)g * GBS * HID;
    unsigned short* hw = p.hbuf + (size_t)((t + 1) & 1) * (BS * HID) + (size_t)g * GBS * HID;

    // ---- stage group h_t (32KB) -> LDS: 2 coherent gload_lds/wave
#pragma unroll
    for (int j = 0; j < 2; ++j) {
      const int i = (wave << 1) + j;
      const int row = i >> 1, half = i & 1;
      const int chunk = ((half << 6) + lane) ^ (row & 7);
      gload_lds16_cc(hb + row * HID + (chunk << 3), smem + (i << 10));
    }
    asm volatile("s_waitcnt vmcnt(0)" ::: "memory");
    __builtin_amdgcn_s_barrier();

    // ---- K loop: 16 x (ds_read_b128 + MFMA), B from registers
    floatx4 acc = {0.f, 0.f, 0.f, 0.f};
#pragma unroll
    for (int kk = 0; kk < 16; ++kk) {
      const int kc = (kh << 6) + (kk << 2) + lh;
      const short8 afr = *(const short8*)(smem + (lr << 11) + ((kc ^ asw) << 4));
      acc = __builtin_amdgcn_mfma_f32_16x16x32_bf16(afr, breg[kk], acc, 0, 0, 0);
    }

    // ---- gate partial sums to gsm (separate LDS region)
    {
      const int gate = nt >> 1, ub16 = (nt & 1) << 4;
#pragma unroll
      for (int r = 0; r < 4; ++r) {
        const int b = (lh << 2) + r;
        gsm[((kh << 2) + gate) * 528 + b * 33 + ub16 + lr] = acc[r] + xv[r];
      }
    }
    __syncthreads();

    // ---- elementwise update + paired coherent publish; hs store deferred
    float hv = 0.f, cn = 0.f;
    if (tid < 512) {
      const int o = b_loc * 33 + u_loc;
      const float ig = gsm[o]            + gsm[4 * 528 + o];
      const float fg = gsm[1 * 528 + o]  + gsm[5 * 528 + o];
      const float gg = gsm[2 * 528 + o]  + gsm[6 * 528 + o];
      const float og = gsm[3 * 528 + o]  + gsm[7 * 528 + o];
      const float iv = 1.f / (1.f + __expf(-ig));
      const float fv = 1.f / (1.f + __expf(-fg));
      const float gv = tanhf(gg);
      const float ov = 1.f / (1.f + __expf(-og));
      cn = fv * creg + iv * gv;
      creg = cn;
      hv = ov * tanhf(cn);
      const unsigned hv16 = (unsigned)f2b(hv);
      const unsigned other = (unsigned)__shfl_xor((int)hv16, 1, 64);
      if ((u_loc & 1) == 0) {
        const unsigned val = (hv16 & 0xFFFFu) | (other << 16);
        const unsigned long long dst =
            (unsigned long long)(hw + (size_t)b_loc * HID + ub_idx * UPB + u_loc);
        asm volatile("global_store_dword %0, %1, off sc0 sc1"
                     :: "v"(dst), "v"(val) : "memory");
      }
    }
    asm volatile("s_waitcnt vmcnt(0)" ::: "memory");  // only the publish
    __syncthreads();
    if (tid == 0) {
      const unsigned long long fdst = (unsigned long long)(p.flags + (size_t)blk * 16);
      const unsigned fval = (unsigned)(t + 1);
      asm volatile("global_store_dword %0, %1, off sc0 sc1"
                   :: "v"(fdst), "v"(fval) : "memory");
    }
    // hs write off the critical path (nt: pure stream to HBM)
    if (tid < 512) {
      __builtin_nontemporal_store(hv,
          p.hs + ((size_t)t * BS + g * GBS + b_loc) * HID + ub_idx * UPB + u_loc);
      if (p.wr_final && t == SEQ - 1) { p.h_final[ci] = hv; p.c_final[ci] = cn; }
    }
  }
  if (tid < 512) p.cbuf[ci] = creg;
}

// ---- gemm body: 128 blocks x 1024 threads (16 waves), 128x128 tile,
// software-pipelined; A reads + xw writes non-temporal (LLC-protecting).
template<int XW_F32>
__device__ __forceinline__ void gemm_body(const FusedArgs& p, char* smem, int bi) {
  if (!p.genable) return;
  short* Al = (short*)smem;            // [128][40]
  short* Bl = (short*)(smem + 10240);  // [128][40]
  const int tid = threadIdx.x;
  const int wave = tid >> 6, lane = tid & 63;
  const int lr = lane & 15, lh = lane >> 4;
  const int wm = wave >> 2, wn = wave & 3;   // 4x4 wave grid, 32x32 each
  const int nmt = p.Mrows >> 7;
  const int tot = nmt << 5;                  // nmt x 32 tiles of 128x128
  const int srow = tid >> 3, scol = (tid & 7) << 2;   // 4 elems/thread

  for (int tt = bi; tt < tot; tt += NBLK) {
    const int m0 = (tt >> 5) << 7, n0 = (tt & 31) << 7;
    const float* aptr = p.A + (size_t)(m0 + srow) * 1024 + scol;
    const short* bptr = p.BT + (size_t)(n0 + srow) * 1024 + scol;
    floatx4 acc[2][2] = {};
    floatx4 fa = __builtin_nontemporal_load((const floatx4*)aptr);
    short4v pb = *(const short4v*)bptr;
    for (int it = 0; it < 32; ++it) {
      __syncthreads();
      {
        short4v s4;
#pragma unroll
        for (int e = 0; e < 4; ++e) s4[e] = (short)f2b(fa[e]);
        *(short4v*)&Al[srow * 40 + scol] = s4;
        *(short4v*)&Bl[srow * 40 + scol] = pb;
      }
      __syncthreads();
      if (it < 31) {
        fa = __builtin_nontemporal_load((const floatx4*)(aptr + ((it + 1) << 5)));
        pb = *(const short4v*)(bptr + ((it + 1) << 5));
      }
      short8 af[2], bf[2];
#pragma unroll
      for (int mt = 0; mt < 2; ++mt)
        af[mt] = *(const short8*)&Al[(wm * 32 + mt * 16 + lr) * 40 + lh * 8];
#pragma unroll
      for (int nt = 0; nt < 2; ++nt)
        bf[nt] = *(const short8*)&Bl[(wn * 32 + nt * 16 + lr) * 40 + lh * 8];
#pragma unroll
      for (int mt = 0; mt < 2; ++mt)
#pragma unroll
        for (int nt = 0; nt < 2; ++nt)
          acc[mt][nt] = __builtin_amdgcn_mfma_f32_16x16x32_bf16(af[mt], bf[nt], acc[mt][nt], 0, 0, 0);
    }
#pragma unroll
    for (int nt = 0; nt < 2; ++nt) {
      const int gc = n0 + wn * 32 + nt * 16 + lr;
      const float bv = p.bias[gc];
#pragma unroll
      for (int mt = 0; mt < 2; ++mt)
#pragma unroll
        for (int r = 0; r < 4; ++r) {
          const int gr = m0 + wm * 32 + mt * 16 + (lh << 2) + r;
          const float v = acc[mt][nt][r] + bv;
          if (XW_F32) __builtin_nontemporal_store(v, (float*)p.dst + (size_t)gr * G4 + gc);
          else        __builtin_nontemporal_store(f2b(v), (unsigned short*)p.dst + (size_t)gr * G4 + gc);
        }
    }
  }
}

// 256 blocks x 1024 threads. LDS 82.5KB forces 1 block/CU:
// scan blocks (0..127) and gemm blocks (128..255) land on different CUs.
template<int XW_F32>
__global__ __launch_bounds__(1024)
void lstm_fused(FusedArgs p) {
  __shared__ __align__(16) char smem[84480];
  if (blockIdx.x < NBLK) scan_body<XW_F32>(p, smem);
  else                   gemm_body<XW_F32>(p, smem, blockIdx.x - NBLK);
}

extern "C" void kernel_launch(void* const* d_in, const int* in_sizes, int n_in,
                              void* d_out, int out_size, void* d_ws, size_t ws_size,
                              hipStream_t stream) {
  const float* x    = (const float*)d_in[0];
  const float* Wii0 = (const float*)d_in[1];
  const float* Wii  = (const float*)d_in[2];
  const float* Whi  = (const float*)d_in[3];
  const float* bias = (const float*)d_in[4];
  float* out  = (float*)d_out;
  float* hs   = out;
  float* hfin = out + (size_t)SEQ * BS * HID;
  float* cfin = hfin + BS * HID;

  char* ws = (char*)d_ws;
  short* WT0 = (short*)ws;
  short* WT1 = WT0 + (size_t)G4 * 1024;
  short* WTh = WT1 + (size_t)G4 * 1024;
  unsigned short* hbuf = (unsigned short*)(WTh + (size_t)G4 * 1024);
  float* cbuf = (float*)(hbuf + 2 * BS * HID);
  unsigned int* flags = (unsigned int*)(cbuf + BS * HID);   // 128 * 64B
  char* tail = (char*)(flags + NBLK * 16);
  const size_t head = (size_t)(tail - ws);
  const size_t avail = (ws_size > head) ? ws_size - head : 0;
  const size_t perT_f32 = (size_t)BS * G4 * 4;   // 1 MiB per timestep
  const size_t perT_b16 = (size_t)BS * G4 * 2;

  // dual (ping-pong) xw buffers for producer/consumer overlap
  int chunk, xwF32;
  if      (avail >= 2 * 128 * perT_f32) { chunk = 128; xwF32 = 1; }
  else if (avail >= 2 * 64  * perT_f32) { chunk = 64;  xwF32 = 1; }
  else if (avail >= 2 * 32  * perT_f32) { chunk = 32;  xwF32 = 1; }
  else if (avail >= 2 * 32  * perT_b16) { chunk = 32;  xwF32 = 0; }
  else                                  { chunk = 8;   xwF32 = 0; }
  const size_t chunkBytes = (size_t)chunk * (xwF32 ? perT_f32 : perT_b16);
  void* xwbuf[2] = { (void*)tail, (void*)(tail + chunkBytes) };
  const int nc = SEQ / chunk;

  wtrans<<<dim3(128, 32), dim3(32, 8), 0, stream>>>(Wii0, WT0);
  wtrans<<<dim3(128, 32), dim3(32, 8), 0, stream>>>(Wii, WT1);
  wtrans<<<dim3(128, 32), dim3(32, 8), 0, stream>>>(Whi, WTh);

  const void* fused_fn = xwF32 ? reinterpret_cast<const void*>(&lstm_fused<1>)
                               : reinterpret_cast<const void*>(&lstm_fused<0>);

  for (int layer = 0; layer < 2; ++layer) {
    hipMemsetAsync(hbuf, 0, 2 * BS * HID * sizeof(unsigned short), stream);
    hipMemsetAsync(cbuf, 0, BS * HID * sizeof(float), stream);
    hipMemsetAsync(flags, 0, NBLK * 16 * sizeof(unsigned int), stream);

    if (layer == 0)   // prologue: only xw chunk not hidden behind a scan
      gemm_xw<<<dim3(32, chunk * BS / 128), dim3(256), 0, stream>>>(
          x, WT0, bias, xwbuf[0], xwF32);

    for (int c = 0; c < nc; ++c) {
      FusedArgs fa;
      fa.xw = xwbuf[c & 1];
      fa.wt_hi = WTh;
      fa.hbuf = hbuf;
      fa.cbuf = cbuf;
      fa.flags = flags;
      fa.hs = hs;
      fa.h_final = layer ? hfin : nullptr;
      fa.c_final = layer ? cfin : nullptr;
      fa.t0 = c * chunk;
      fa.t1 = (c + 1) * chunk;
      fa.wr_final = layer;
      // producer: xw for the next chunk (possibly the next layer's first)
      fa.bias = bias;
      fa.dst = xwbuf[(c + 1) & 1];
      fa.Mrows = chunk * BS;
      if (c < nc - 1) {
        fa.A = (layer ? hs : x) + (size_t)(c + 1) * chunk * BS * 1024;
        fa.BT = layer ? WT1 : WT0;
        fa.genable = 1;
      } else if (layer == 0) {
        fa.A = hs;                 // layer 1, chunk 0 (hs fully written)
        fa.BT = WT1;
        fa.genable = 1;
      } else {
        fa.A = x; fa.BT = WT1;
        fa.genable = 0;
      }
      void* args[] = { &fa };
      hipLaunchCooperativeKernel(fused_fn, dim3(2 * NBLK), dim3(1024), args, 0u, stream);
    }
  }
}

// Round 9
// 3941.043 us; speedup vs baseline: 1.3596x; 1.3596x over previous
//
#include <hip/hip_runtime.h>

typedef __attribute__((ext_vector_type(8))) short short8;
typedef __attribute__((ext_vector_type(4))) short short4v;
typedef __attribute__((ext_vector_type(4))) float floatx4;

#define SEQ 512
#define BS  64
#define HID 1024
#define G4  4096
#define NBLK 128
#define NGRP 4    // batch groups
#define BPG  32   // blocks per group
#define GBS  16   // batch rows per group
#define UPB  32   // hidden units per block

__device__ __forceinline__ unsigned short f2b(float f) {
  union { float f; unsigned u; } v; v.f = f;
  return (unsigned short)((v.u + 0x7FFFu + ((v.u >> 16) & 1u)) >> 16);
}
__device__ __forceinline__ float b2f(unsigned short s) {
  union { unsigned u; float f; } v; v.u = ((unsigned)s) << 16;
  return v.f;
}

// device-coherent (cross-XCD) async global->LDS: aux=17 = SC0|SC1
__device__ __forceinline__ void gload_lds16_cc(const void* g, void* l) {
  __builtin_amdgcn_global_load_lds(
      (const __attribute__((address_space(1))) unsigned int*)g,
      (__attribute__((address_space(3))) unsigned int*)l,
      16, 0, 17);
}

// ---- weight transpose+convert: W[1024][4096] f32 -> WT[4096][1024] bf16
__global__ void wtrans(const float* __restrict__ W, short* __restrict__ WT) {
  __shared__ float tile[32][33];
  const int tx = threadIdx.x, ty = threadIdx.y;
  const int n0 = blockIdx.x << 5, k0 = blockIdx.y << 5;
#pragma unroll
  for (int i = 0; i < 32; i += 8)
    tile[ty + i][tx] = W[(size_t)(k0 + ty + i) * G4 + n0 + tx];
  __syncthreads();
#pragma unroll
  for (int i = 0; i < 32; i += 8)
    WT[(size_t)(n0 + ty + i) * 1024 + k0 + tx] = (short)f2b(tile[tx][ty + i]);
}

// ---- f32 -> bf16 convert (x into the shared A buffer)
__global__ __launch_bounds__(256)
void conv_bf16(const float* __restrict__ in, unsigned short* __restrict__ out) {
  const size_t i = ((size_t)blockIdx.x * 256 + threadIdx.x) * 8;
  const floatx4 a = *(const floatx4*)(in + i);
  const floatx4 b = *(const floatx4*)(in + i + 4);
  short8 s;
#pragma unroll
  for (int e = 0; e < 4; ++e) { s[e] = (short)f2b(a[e]); s[4 + e] = (short)f2b(b[e]); }
  *(short8*)(out + i) = s;
}

struct FusedArgs {
  // scan (blocks 0..127): recurrence for chunk [t0,t1) reading bf16 xw
  const unsigned short* xw;
  const short* wt_hi;
  unsigned short* hbuf;    // [2][64*1024] bf16 ping-pong (coherent traffic)
  float* cbuf;             // [64*1024] f32 persistent cell state
  unsigned int* flags;     // [NBLK] u32 padded to 64B
  float* hs;               // [512][64][1024] f32 output
  unsigned short* hsb;     // shared bf16 buffer: x rows become h rows
  float* h_final;
  float* c_final;
  int t0, t1, wr_final;
  // gemm (blocks 128..255): bf16 xw for the NEXT chunk -> dst
  const short* A;          // bf16 [Mrows][1024]
  const short* BT;         // WT [4096][1024] bf16
  const float* bias;
  unsigned short* dst;
  int Mrows, genable;
};

// ---- scan body: r5/r7 geometry; bf16 xw; paired publish; throttled poll
__device__ __forceinline__ void scan_body(const FusedArgs& p, char* smem) {
  // [0,32768): h tile [16 rows][2048B] XOR-swizzled; [32768,+16896): gsm
  float* gsm = (float*)(smem + 32768);
  const int tid = threadIdx.x;
  const int wave = tid >> 6, lane = tid & 63;
  const int lr = lane & 15, lh = lane >> 4;
  const int nt = wave >> 1;              // N tile 0..7
  const int kh = wave & 1;               // K half 0..1
  const int blk = blockIdx.x;
  const int g = blk >> 5;                // batch group 0..3
  const int ub_idx = blk & 31;           // unit-block within hidden dim
  const int gcol = ((nt >> 1) << 10) + ub_idx * UPB + ((nt & 1) << 4) + lr;

  short8 breg[16];
  {
    const short* wp = p.wt_hi + (size_t)gcol * HID + (kh << 9) + (lh << 3);
#pragma unroll
    for (int kk = 0; kk < 16; ++kk) breg[kk] = *(const short8*)(wp + (kk << 5));
  }

  const int b_loc = tid >> 5, u_loc = tid & 31;
  const int ci = ((g * GBS + b_loc) << 10) + ub_idx * UPB + u_loc;
  float creg = (tid < 512) ? p.cbuf[ci] : 0.f;

  const int asw = lr & 7;
  const unsigned long long fad =
      (unsigned long long)(p.flags + ((size_t)(g * BPG) + (lane & 31)) * 16);

  for (int t = p.t0; t < p.t1; ++t) {
    // ---- xw prefetch BEFORE the poll: latency rides under the flag wait
    float xv[4] = {0.f, 0.f, 0.f, 0.f};
    if (kh == 0) {
#pragma unroll
      for (int r = 0; r < 4; ++r) {
        const size_t rowi = (size_t)(t - p.t0) * BS + g * GBS + (lh << 2) + r;
        xv[r] = b2f(p.xw[rowi * G4 + gcol]);
      }
    }

    // ---- barrier-in: wait until the group has published h for step t
    if (t > 0 && wave == 0) {
      unsigned f0;
      for (;;) {
        asm volatile("global_load_dword %0, %1, off sc0 sc1\n\t"
                     "s_waitcnt vmcnt(0)"
                     : "=v"(f0) : "v"(fad) : "memory");
        if (__all(f0 >= (unsigned)t)) break;
        __builtin_amdgcn_s_sleep(1);
      }
    }
    __syncthreads();

    const unsigned short* hb = p.hbuf + (size_t)(t & 1) * (BS * HID) + (size_t)g * GBS * HID;
    unsigned short* hw = p.hbuf + (size_t)((t + 1) & 1) * (BS * HID) + (size_t)g * GBS * HID;

    // ---- stage group h_t (32KB) -> LDS: 2 coherent gload_lds/wave
#pragma unroll
    for (int j = 0; j < 2; ++j) {
      const int i = (wave << 1) + j;
      const int row = i >> 1, half = i & 1;
      const int chunk = ((half << 6) + lane) ^ (row & 7);
      gload_lds16_cc(hb + row * HID + (chunk << 3), smem + (i << 10));
    }
    asm volatile("s_waitcnt vmcnt(0)" ::: "memory");
    __builtin_amdgcn_s_barrier();

    // ---- K loop: 16 x (ds_read_b128 + MFMA), B from registers
    floatx4 acc = {0.f, 0.f, 0.f, 0.f};
#pragma unroll
    for (int kk = 0; kk < 16; ++kk) {
      const int kc = (kh << 6) + (kk << 2) + lh;
      const short8 afr = *(const short8*)(smem + (lr << 11) + ((kc ^ asw) << 4));
      acc = __builtin_amdgcn_mfma_f32_16x16x32_bf16(afr, breg[kk], acc, 0, 0, 0);
    }

    // ---- gate partial sums to gsm (separate LDS region)
    {
      const int gate = nt >> 1, ub16 = (nt & 1) << 4;
#pragma unroll
      for (int r = 0; r < 4; ++r) {
        const int b = (lh << 2) + r;
        gsm[((kh << 2) + gate) * 528 + b * 33 + ub16 + lr] = acc[r] + xv[r];
      }
    }
    __syncthreads();

    // ---- elementwise update + paired coherent publish; hs/hsb deferred
    float hv = 0.f, cn = 0.f;
    unsigned hv16 = 0;
    if (tid < 512) {
      const int o = b_loc * 33 + u_loc;
      const float ig = gsm[o]            + gsm[4 * 528 + o];
      const float fg = gsm[1 * 528 + o]  + gsm[5 * 528 + o];
      const float gg = gsm[2 * 528 + o]  + gsm[6 * 528 + o];
      const float og = gsm[3 * 528 + o]  + gsm[7 * 528 + o];
      const float iv = 1.f / (1.f + __expf(-ig));
      const float fv = 1.f / (1.f + __expf(-fg));
      const float gv = tanhf(gg);
      const float ov = 1.f / (1.f + __expf(-og));
      cn = fv * creg + iv * gv;
      creg = cn;
      hv = ov * tanhf(cn);
      hv16 = (unsigned)f2b(hv);
      const unsigned other = (unsigned)__shfl_xor((int)hv16, 1, 64);
      if ((u_loc & 1) == 0) {
        const unsigned val = (hv16 & 0xFFFFu) | (other << 16);
        const unsigned long long dst =
            (unsigned long long)(hw + (size_t)b_loc * HID + ub_idx * UPB + u_loc);
        asm volatile("global_store_dword %0, %1, off sc0 sc1"
                     :: "v"(dst), "v"(val) : "memory");
      }
    }
    asm volatile("s_waitcnt vmcnt(0)" ::: "memory");  // only the publish
    __syncthreads();
    if (tid == 0) {
      const unsigned long long fdst = (unsigned long long)(p.flags + (size_t)blk * 16);
      const unsigned fval = (unsigned)(t + 1);
      asm volatile("global_store_dword %0, %1, off sc0 sc1"
                   :: "v"(fdst), "v"(fval) : "memory");
    }
    // hs (f32 out) + hsb (bf16 A-buffer) writes off the critical path
    if (tid < 512) {
      const size_t oidx = ((size_t)t * BS + g * GBS + b_loc) * HID + ub_idx * UPB + u_loc;
      p.hs[oidx] = hv;
      p.hsb[oidx] = (unsigned short)hv16;
      if (p.wr_final && t == SEQ - 1) { p.h_final[ci] = hv; p.c_final[ci] = cn; }
    }
  }
  if (tid < 512) p.cbuf[ci] = creg;
}

// ---- gemm body: bf16 A and B, 128x128 tile, software-pipelined
__device__ __forceinline__ void gemm_body(const FusedArgs& p, char* smem, int bi) {
  if (!p.genable) return;
  short* Al = (short*)smem;            // [128][40]
  short* Bl = (short*)(smem + 10240);  // [128][40]
  const int tid = threadIdx.x;
  const int wave = tid >> 6, lane = tid & 63;
  const int lr = lane & 15, lh = lane >> 4;
  const int wm = wave >> 2, wn = wave & 3;   // 4x4 wave grid, 32x32 each
  const int nmt = p.Mrows >> 7;
  const int tot = nmt << 5;                  // nmt x 32 tiles of 128x128
  const int srow = tid >> 3, scol = (tid & 7) << 2;   // 4 elems/thread

  for (int tt = bi; tt < tot; tt += NBLK) {
    const int m0 = (tt >> 5) << 7, n0 = (tt & 31) << 7;
    const short* aptr = p.A + (size_t)(m0 + srow) * 1024 + scol;
    const short* bptr = p.BT + (size_t)(n0 + srow) * 1024 + scol;
    floatx4 acc[2][2] = {};
    short4v pa = *(const short4v*)aptr;
    short4v pb = *(const short4v*)bptr;
    for (int it = 0; it < 32; ++it) {
      __syncthreads();
      *(short4v*)&Al[srow * 40 + scol] = pa;
      *(short4v*)&Bl[srow * 40 + scol] = pb;
      __syncthreads();
      if (it < 31) {
        pa = *(const short4v*)(aptr + ((it + 1) << 5));
        pb = *(const short4v*)(bptr + ((it + 1) << 5));
      }
      short8 af[2], bf[2];
#pragma unroll
      for (int mt = 0; mt < 2; ++mt)
        af[mt] = *(const short8*)&Al[(wm * 32 + mt * 16 + lr) * 40 + lh * 8];
#pragma unroll
      for (int nt = 0; nt < 2; ++nt)
        bf[nt] = *(const short8*)&Bl[(wn * 32 + nt * 16 + lr) * 40 + lh * 8];
#pragma unroll
      for (int mt = 0; mt < 2; ++mt)
#pragma unroll
        for (int nt = 0; nt < 2; ++nt)
          acc[mt][nt] = __builtin_amdgcn_mfma_f32_16x16x32_bf16(af[mt], bf[nt], acc[mt][nt], 0, 0, 0);
    }
#pragma unroll
    for (int nt = 0; nt < 2; ++nt) {
      const int gc = n0 + wn * 32 + nt * 16 + lr;
      const float bv = p.bias[gc];
#pragma unroll
      for (int mt = 0; mt < 2; ++mt)
#pragma unroll
        for (int r = 0; r < 4; ++r) {
          const int gr = m0 + wm * 32 + mt * 16 + (lh << 2) + r;
          p.dst[(size_t)gr * G4 + gc] = f2b(acc[mt][nt][r] + bv);
        }
    }
  }
}

// prologue: pure-gemm dispatch (same body, 128 blocks)
__global__ __launch_bounds__(1024)
void gemm_pre(FusedArgs p) {
  __shared__ __align__(16) char smem[84480];
  gemm_body(p, smem, blockIdx.x);
}

// 256 blocks x 1024 threads. LDS 82.5KB forces 1 block/CU:
// scan blocks (0..127) and gemm blocks (128..255) land on different CUs.
__global__ __launch_bounds__(1024)
void lstm_fused(FusedArgs p) {
  __shared__ __align__(16) char smem[84480];
  if (blockIdx.x < NBLK) scan_body(p, smem);
  else                   gemm_body(p, smem, blockIdx.x - NBLK);
}

extern "C" void kernel_launch(void* const* d_in, const int* in_sizes, int n_in,
                              void* d_out, int out_size, void* d_ws, size_t ws_size,
                              hipStream_t stream) {
  const float* x    = (const float*)d_in[0];
  const float* Wii0 = (const float*)d_in[1];
  const float* Wii  = (const float*)d_in[2];
  const float* Whi  = (const float*)d_in[3];
  const float* bias = (const float*)d_in[4];
  float* out  = (float*)d_out;
  float* hs   = out;
  float* hfin = out + (size_t)SEQ * BS * HID;
  float* cfin = hfin + BS * HID;

  char* ws = (char*)d_ws;
  short* WT0 = (short*)ws;
  short* WT1 = WT0 + (size_t)G4 * 1024;
  short* WTh = WT1 + (size_t)G4 * 1024;
  unsigned short* hbuf = (unsigned short*)(WTh + (size_t)G4 * 1024);
  float* cbuf = (float*)(hbuf + 2 * BS * HID);
  unsigned int* flags = (unsigned int*)(cbuf + BS * HID);   // 128 * 64B
  unsigned short* xb = (unsigned short*)(flags + NBLK * 16); // shared x/h bf16
  char* tail = (char*)(xb + (size_t)SEQ * BS * HID);
  const size_t head = (size_t)(tail - ws);
  const size_t avail = (ws_size > head) ? ws_size - head : 0;
  const size_t perT = (size_t)BS * G4 * 2;   // 512 KiB per timestep (bf16)

  int chunk;
  if      (avail >= 2 * 128 * perT) chunk = 128;
  else if (avail >= 2 * 64  * perT) chunk = 64;
  else if (avail >= 2 * 32  * perT) chunk = 32;
  else                              chunk = 8;
  const size_t chunkBytes = (size_t)chunk * perT;
  unsigned short* xwbuf[2] = { (unsigned short*)tail,
                               (unsigned short*)(tail + chunkBytes) };
  const int nc = SEQ / chunk;

  wtrans<<<dim3(128, 32), dim3(32, 8), 0, stream>>>(Wii0, WT0);
  wtrans<<<dim3(128, 32), dim3(32, 8), 0, stream>>>(Wii, WT1);
  wtrans<<<dim3(128, 32), dim3(32, 8), 0, stream>>>(Whi, WTh);
  conv_bf16<<<dim3((SEQ * BS * HID) / (256 * 8)), dim3(256), 0, stream>>>(x, xb);

  for (int layer = 0; layer < 2; ++layer) {
    hipMemsetAsync(hbuf, 0, 2 * BS * HID * sizeof(unsigned short), stream);
    hipMemsetAsync(cbuf, 0, BS * HID * sizeof(float), stream);
    hipMemsetAsync(flags, 0, NBLK * 16 * sizeof(unsigned int), stream);

    if (layer == 0) {  // prologue: only xw chunk not hidden behind a scan
      FusedArgs pa = {};
      pa.A = (const short*)xb;
      pa.BT = WT0;
      pa.bias = bias;
      pa.dst = xwbuf[0];
      pa.Mrows = chunk * BS;
      pa.genable = 1;
      gemm_pre<<<dim3(NBLK), dim3(1024), 0, stream>>>(pa);
    }

    for (int c = 0; c < nc; ++c) {
      FusedArgs fa;
      fa.xw = xwbuf[c & 1];
      fa.wt_hi = WTh;
      fa.hbuf = hbuf;
      fa.cbuf = cbuf;
      fa.flags = flags;
      fa.hs = hs;
      fa.hsb = xb;
      fa.h_final = layer ? hfin : nullptr;
      fa.c_final = layer ? cfin : nullptr;
      fa.t0 = c * chunk;
      fa.t1 = (c + 1) * chunk;
      fa.wr_final = layer;
      // producer: bf16 xw for the next chunk (wraps to next layer's first).
      // A rows [(c+1)%nc * chunk*BS ...) of the shared buffer hold x (layer 0)
      // or previous-layer h (after the scan passed them) — always the right
      // operand by construction (row t is overwritten one dispatch AFTER its
      // last read).
      fa.bias = bias;
      fa.dst = xwbuf[(c + 1) & 1];
      fa.Mrows = chunk * BS;
      const int nxt = ((c + 1) % nc) * chunk * BS;
      fa.A = (const short*)(xb + (size_t)nxt * HID);
      fa.BT = (layer == 0 && c < nc - 1) ? WT0 : WT1;
      fa.genable = !(layer == 1 && c == nc - 1);
      void* args[] = { &fa };
      hipLaunchCooperativeKernel(reinterpret_cast<const void*>(&lstm_fused),
                                 dim3(2 * NBLK), dim3(1024), args, 0u, stream);
    }
  }
}